// Round 2
// baseline (964.093 us; speedup 1.0000x reference)
//
#include <hip/hip_runtime.h>
#include <cstdint>

typedef unsigned short u16;
typedef u16   u16x8 __attribute__((ext_vector_type(8)));
typedef short s16x8 __attribute__((ext_vector_type(8)));
typedef float f32x4 __attribute__((ext_vector_type(4)));

__device__ __forceinline__ u16 f2bf(float f) {
  union { float f; unsigned u; } v; v.f = f;
  unsigned u = v.u;
  return (u16)((u + 0x7fffu + ((u >> 16) & 1u)) >> 16);
}

__device__ __forceinline__ void gld_lds16(const u16* g, u16* l) {
  __builtin_amdgcn_global_load_lds((const __attribute__((address_space(1))) void*)g,
                                   (__attribute__((address_space(3))) void*)l, 16, 0, 0);
}

// ---------------- elementwise cast fp32 -> bf16 ----------------
__global__ void cast_f32_bf16_k(const float* __restrict__ in, u16* __restrict__ out) {
  size_t i = ((size_t)blockIdx.x * 256 + threadIdx.x) * 8;
  float4 a = *(const float4*)(in + i);
  float4 b = *(const float4*)(in + i + 4);
  u16x8 r;
  r[0] = f2bf(a.x); r[1] = f2bf(a.y); r[2] = f2bf(a.z); r[3] = f2bf(a.w);
  r[4] = f2bf(b.x); r[5] = f2bf(b.y); r[6] = f2bf(b.z); r[7] = f2bf(b.w);
  *(u16x8*)(out + i) = r;
}

// ---------------- transpose+cast fp32 [R][Cin] -> bf16 [Cin][R] ----------------
__global__ void transpose_cast_f32_k(const float* __restrict__ in, u16* __restrict__ outp,
                                     int R, int Cin) {
  __shared__ u16 tile[64][72];
  const int c0 = blockIdx.x * 64, r0 = blockIdx.y * 64;
  const int t = threadIdx.x;
  const int r = t >> 2, cs = (t & 3) * 16;
  const float* src = in + (size_t)(r0 + r) * Cin + c0 + cs;
#pragma unroll
  for (int q = 0; q < 4; ++q) {
    float4 v = *(const float4*)(src + q * 4);
    tile[r][cs + q * 4 + 0] = f2bf(v.x);
    tile[r][cs + q * 4 + 1] = f2bf(v.y);
    tile[r][cs + q * 4 + 2] = f2bf(v.z);
    tile[r][cs + q * 4 + 3] = f2bf(v.w);
  }
  __syncthreads();
  u16x8 w0, w1;
#pragma unroll
  for (int q = 0; q < 8; ++q) { w0[q] = tile[cs + q][r]; w1[q] = tile[cs + 8 + q][r]; }
  u16* dst = outp + (size_t)(c0 + r) * R + r0 + cs;
  *(u16x8*)dst = w0;
  *(u16x8*)(dst + 8) = w1;
}

// ---------------- transpose bf16 V [bh][T][D] -> Vt [bh][D][T] ----------------
__global__ void transpose_v_k(const u16* __restrict__ V, u16* __restrict__ Vt) {
  __shared__ u16 tile[64][72];
  const int t0 = blockIdx.x * 64, d0 = blockIdx.y * 64, bh = blockIdx.z;
  const int t = threadIdx.x;
  const int r = t >> 2, cs = (t & 3) * 16;
  const u16* src = V + ((size_t)bh * 2048 + t0 + r) * 128 + d0 + cs;
  u16x8 a0 = *(const u16x8*)src;
  u16x8 a1 = *(const u16x8*)(src + 8);
#pragma unroll
  for (int q = 0; q < 8; ++q) { tile[r][cs + q] = a0[q]; tile[r][cs + 8 + q] = a1[q]; }
  __syncthreads();
  u16x8 w0, w1;
#pragma unroll
  for (int q = 0; q < 8; ++q) { w0[q] = tile[cs + q][r]; w1[q] = tile[cs + 8 + q][r]; }
  u16* dst = Vt + ((size_t)bh * 128 + d0 + r) * 2048 + t0 + cs;
  *(u16x8*)dst = w0;
  *(u16x8*)(dst + 8) = w1;
}

// ---------------- GEMM 256x256 tile, BK=32, 8 waves, 3-buffer counted-vmcnt pipeline ----
// C[M,N] = A[M,K] * Bt[N,K]^T + bias.  EPI 0: scatter Q/K/V bf16 [B,H,T,D]; EPI 1: fp32 out.
template <int EPI>
__global__ __launch_bounds__(512, 2) void gemm256(
    const u16* __restrict__ A, const u16* __restrict__ Bt,
    const float* __restrict__ bias,
    u16* __restrict__ o0, u16* __restrict__ o1, u16* __restrict__ o2,
    float* __restrict__ ofp, int Ntiles, int Kdim) {
  // per buffer: A 256x32 (16KB) + B 256x32 (16KB), k-major 16B chunks [khi*256+row]
  __shared__ __align__(128) u16 sm[49152];  // 3 buffers x 32 KB = 96 KB
  const int nwg = gridDim.x;
  const int orig = blockIdx.x;
  const int qq = nwg >> 3;                      // grids are multiples of 8
  const int bid = (orig & 7) * qq + (orig >> 3);  // bijective XCD swizzle
  const int mt = bid / Ntiles, nt = bid % Ntiles;
  const int tid = threadIdx.x, lane = tid & 63, wave = tid >> 6;
  const int wr = wave >> 2, wc = wave & 3;      // 2M x 4N waves, 128x64 out each
  f32x4 acc[8][4] = {};
  const int nK = Kdim >> 5;

#define STAGE(b, kt)                                                          \
  do {                                                                        \
    int k0 = (kt) << 5;                                                       \
    _Pragma("unroll")                                                         \
    for (int j = 0; j < 2; ++j) {                                             \
      int ci = j * 512 + tid;                                                 \
      int khi = ci >> 8, row = ci & 255;                                      \
      gld_lds16(A + (size_t)(mt * 256 + row) * Kdim + k0 + khi * 8,           \
                &sm[(b) * 16384 + (j * 512 + wave * 64) * 8]);                \
      gld_lds16(Bt + (size_t)(nt * 256 + row) * Kdim + k0 + khi * 8,          \
                &sm[(b) * 16384 + 8192 + (j * 512 + wave * 64) * 8]);         \
    }                                                                         \
  } while (0)

  STAGE(0, 0);
  STAGE(1, 1);
  for (int kt = 0; kt < nK; ++kt) {
    // tile kt's 4 loads are the oldest 4 of (at most) 8 outstanding
    if (kt + 1 < nK) asm volatile("s_waitcnt vmcnt(4)" ::: "memory");
    else             asm volatile("s_waitcnt vmcnt(0)" ::: "memory");
    __builtin_amdgcn_s_barrier();   // all waves: tile kt staged; buf (kt+2)%3 free
    asm volatile("" ::: "memory");
    if (kt + 2 < nK) STAGE((kt + 2) % 3, kt + 2);
    const u16* Ab = &sm[(kt % 3) * 16384];
    const u16* Bb = Ab + 8192;
    s16x8 af[8], bf[4];
#pragma unroll
    for (int mi = 0; mi < 8; ++mi)
      af[mi] = *(const s16x8*)&Ab[((lane >> 4) * 256 + wr * 128 + mi * 16 + (lane & 15)) * 8];
#pragma unroll
    for (int ni = 0; ni < 4; ++ni)
      bf[ni] = *(const s16x8*)&Bb[((lane >> 4) * 256 + wc * 64 + ni * 16 + (lane & 15)) * 8];
    __builtin_amdgcn_s_setprio(1);
#pragma unroll
    for (int mi = 0; mi < 8; ++mi)
#pragma unroll
      for (int ni = 0; ni < 4; ++ni)
        acc[mi][ni] = __builtin_amdgcn_mfma_f32_16x16x32_bf16(af[mi], bf[ni], acc[mi][ni], 0, 0, 0);
    __builtin_amdgcn_s_setprio(0);
  }
#undef STAGE

  const int row0 = mt * 256 + wr * 128;
  const int col0 = nt * 256 + wc * 64;
  float bcol[4];
#pragma unroll
  for (int ni = 0; ni < 4; ++ni) bcol[ni] = bias[col0 + ni * 16 + (lane & 15)];
  if constexpr (EPI == 0) {
#pragma unroll
    for (int ni = 0; ni < 4; ++ni) {
      int cc = col0 + ni * 16 + (lane & 15);
      int which = cc >> 11, h = (cc >> 7) & 15, d = cc & 127;
      u16* o = (which == 0) ? o0 : (which == 1) ? o1 : o2;
#pragma unroll
      for (int mi = 0; mi < 8; ++mi)
#pragma unroll
        for (int j = 0; j < 4; ++j) {
          int row = row0 + mi * 16 + (lane >> 4) * 4 + j;
          int bb = row >> 11, t = row & 2047;
          o[(((size_t)bb * 16 + h) * 2048 + t) * 128 + d] = f2bf(acc[mi][ni][j] + bcol[ni]);
        }
    }
  } else {
#pragma unroll
    for (int mi = 0; mi < 8; ++mi)
#pragma unroll
      for (int j = 0; j < 4; ++j) {
        int row = row0 + mi * 16 + (lane >> 4) * 4 + j;
#pragma unroll
        for (int ni = 0; ni < 4; ++ni)
          ofp[(size_t)row * 2048 + col0 + ni * 16 + (lane & 15)] = acc[mi][ni][j] + bcol[ni];
      }
  }
}

// ---------------- flash attention: 64 q-rows/block, 4 waves x 16 rows ----------------
__global__ __launch_bounds__(256, 2) void attn_k(
    const u16* __restrict__ Q, const u16* __restrict__ Kg,
    const u16* __restrict__ Vt, u16* __restrict__ Y) {
  __shared__ u16 Ks[8192];        // 16 dhi x 64 key, 16B chunks
  __shared__ u16 Vs[8192];        // 8 khi x 128 d, 16B chunks
  __shared__ u16 Ps[4][16 * 72];  // per-wave P tile, padded rows
  const int qt = blockIdx.x, bh = blockIdx.y;
  const int tid = threadIdx.x, lane = tid & 63, wave = tid >> 6;
  const int r0 = qt * 64 + wave * 16;
  const size_t bhT = (size_t)bh * 2048;

  s16x8 qf[4];
#pragma unroll
  for (int kk = 0; kk < 4; ++kk)
    qf[kk] = *(const s16x8*)&Q[(bhT + r0 + (lane & 15)) * 128 + kk * 32 + (lane >> 4) * 8];

  f32x4 o[8] = {};
  float m_[4], l_[4];
#pragma unroll
  for (int j = 0; j < 4; ++j) { m_[j] = -1e30f; l_[j] = 0.f; }
  const float sc = 0.08838834764831845f * 1.4426950408889634f;  // 1/sqrt(128) * log2(e)

  for (int it = 0; it <= qt; ++it) {
    const int j0 = it * 64;
    __syncthreads();  // previous tile's LDS reads done before restage
#pragma unroll
    for (int j = 0; j < 4; ++j) {
      int idx = (wave * 4 + j) * 64 + lane;
      int dhi = idx >> 6, key = idx & 63;
      gld_lds16(Kg + (bhT + j0 + key) * 128 + dhi * 8, &Ks[(wave * 4 + j) * 512]);
      int khi = idx >> 7, d = idx & 127;
      gld_lds16(Vt + ((size_t)bh * 128 + d) * 2048 + j0 + khi * 8, &Vs[(wave * 4 + j) * 512]);
    }
    __syncthreads();  // drains vmcnt: K/V staged

    // S = Q K^T (per wave: 16 q-rows x 64 keys)
    f32x4 s[4] = {};
#pragma unroll
    for (int nc = 0; nc < 4; ++nc) {
#pragma unroll
      for (int kk = 0; kk < 4; ++kk) {
        s16x8 kf = *(const s16x8*)&Ks[((kk * 4 + (lane >> 4)) * 64 + nc * 16 + (lane & 15)) * 8];
        s[nc] = __builtin_amdgcn_mfma_f32_16x16x32_bf16(qf[kk], kf, s[nc], 0, 0, 0);
      }
    }
    const bool lastT = (it == qt);
    float rmax[4];
#pragma unroll
    for (int j = 0; j < 4; ++j) rmax[j] = -1e30f;
#pragma unroll
    for (int nc = 0; nc < 4; ++nc)
#pragma unroll
      for (int j = 0; j < 4; ++j) {
        float v = s[nc][j] * sc;
        if (lastT && (j0 + nc * 16 + (lane & 15)) > (r0 + (lane >> 4) * 4 + j)) v = -1e30f;
        s[nc][j] = v;
        rmax[j] = fmaxf(rmax[j], v);
      }
#pragma unroll
    for (int off = 1; off < 16; off <<= 1)
#pragma unroll
      for (int j = 0; j < 4; ++j) rmax[j] = fmaxf(rmax[j], __shfl_xor(rmax[j], off));

    float al[4], rsum[4];
#pragma unroll
    for (int j = 0; j < 4; ++j) {
      float mn = fmaxf(m_[j], rmax[j]);
      al[j] = exp2f(m_[j] - mn);
      m_[j] = mn;
      rsum[j] = 0.f;
    }
#pragma unroll
    for (int nc = 0; nc < 4; ++nc)
#pragma unroll
      for (int j = 0; j < 4; ++j) {
        float p = exp2f(s[nc][j] - m_[j]);
        rsum[j] += p;
        Ps[wave][((lane >> 4) * 4 + j) * 72 + nc * 16 + (lane & 15)] = f2bf(p);
      }
#pragma unroll
    for (int off = 1; off < 16; off <<= 1)
#pragma unroll
      for (int j = 0; j < 4; ++j) rsum[j] += __shfl_xor(rsum[j], off);
#pragma unroll
    for (int j = 0; j < 4; ++j) l_[j] = l_[j] * al[j] + rsum[j];
#pragma unroll
    for (int di = 0; di < 8; ++di)
#pragma unroll
      for (int j = 0; j < 4; ++j) o[di][j] *= al[j];

    // O += P V  (P via LDS round-trip to get A-fragment layout)
#pragma unroll
    for (int kk2 = 0; kk2 < 2; ++kk2) {
      s16x8 pf = *(const s16x8*)&Ps[wave][(lane & 15) * 72 + kk2 * 32 + (lane >> 4) * 8];
#pragma unroll
      for (int di = 0; di < 8; ++di) {
        s16x8 vf = *(const s16x8*)&Vs[((kk2 * 4 + (lane >> 4)) * 128 + di * 16 + (lane & 15)) * 8];
        o[di] = __builtin_amdgcn_mfma_f32_16x16x32_bf16(pf, vf, o[di], 0, 0, 0);
      }
    }
  }

  float rl[4];
#pragma unroll
  for (int j = 0; j < 4; ++j) rl[j] = 1.0f / l_[j];
  const int b = bh >> 4, h = bh & 15;
#pragma unroll
  for (int di = 0; di < 8; ++di)
#pragma unroll
    for (int j = 0; j < 4; ++j) {
      int row = b * 2048 + r0 + (lane >> 4) * 4 + j;
      int col = h * 128 + di * 16 + (lane & 15);
      Y[(size_t)row * 2048 + col] = f2bf(o[di][j] * rl[j]);
    }
}

extern "C" void kernel_launch(void* const* d_in, const int* in_sizes, int n_in,
                              void* d_out, int out_size, void* d_ws, size_t ws_size,
                              hipStream_t stream) {
  const float* x      = (const float*)d_in[0];
  const float* w_attn = (const float*)d_in[1];
  const float* b_attn = (const float*)d_in[2];
  const float* w_proj = (const float*)d_in[3];
  const float* b_proj = (const float*)d_in[4];
  float* out = (float*)d_out;

  char* ws = (char*)d_ws;
  u16* xb  = (u16*)(ws);                      // x bf16 [8192][2048]
  u16* waT = (u16*)(ws + 33554432ull);        // w_attn^T bf16 [6144][2048]
  u16* wpT = (u16*)(ws + 58720256ull);        // w_proj^T bf16 [2048][2048]
  u16* Qb  = (u16*)(ws + 67108864ull);        // [B,H,T,D]
  u16* Kb  = (u16*)(ws + 100663296ull);
  u16* Vb  = (u16*)(ws + 134217728ull);
  u16* Vtb = (u16*)(ws + 167772160ull);       // [B,H,D,T]
  u16* Yb  = xb;                              // reuse (xb dead after gemm1)

  cast_f32_bf16_k<<<8192, 256, 0, stream>>>(x, xb);
  transpose_cast_f32_k<<<dim3(96, 32), 256, 0, stream>>>(w_attn, waT, 2048, 6144);
  transpose_cast_f32_k<<<dim3(32, 32), 256, 0, stream>>>(w_proj, wpT, 2048, 2048);
  gemm256<0><<<32 * 24, 512, 0, stream>>>(xb, waT, b_attn, Qb, Kb, Vb, nullptr, 24, 2048);
  transpose_v_k<<<dim3(32, 2, 64), 256, 0, stream>>>(Vb, Vtb);
  attn_k<<<dim3(32, 64), 256, 0, stream>>>(Qb, Kb, Vtb, Yb);
  gemm256<1><<<32 * 8, 512, 0, stream>>>(Yb, wpT, b_proj, nullptr, nullptr, nullptr, out, 8, 2048);
}

// Round 3
// 735.399 us; speedup vs baseline: 1.3110x; 1.3110x over previous
//
#include <hip/hip_runtime.h>
#include <cstdint>

typedef unsigned short u16;
typedef u16   u16x8 __attribute__((ext_vector_type(8)));
typedef short s16x8 __attribute__((ext_vector_type(8)));
typedef float f32x4 __attribute__((ext_vector_type(4)));

__device__ __forceinline__ u16 f2bf(float f) {
  union { float f; unsigned u; } v; v.f = f;
  unsigned u = v.u;
  return (u16)((u + 0x7fffu + ((u >> 16) & 1u)) >> 16);
}

__device__ __forceinline__ void gld_lds16(const u16* g, u16* l) {
  __builtin_amdgcn_global_load_lds((const __attribute__((address_space(1))) void*)g,
                                   (__attribute__((address_space(3))) void*)l, 16, 0, 0);
}

// ---------------- elementwise cast fp32 -> bf16 ----------------
__global__ void cast_f32_bf16_k(const float* __restrict__ in, u16* __restrict__ out) {
  size_t i = ((size_t)blockIdx.x * 256 + threadIdx.x) * 8;
  float4 a = *(const float4*)(in + i);
  float4 b = *(const float4*)(in + i + 4);
  u16x8 r;
  r[0] = f2bf(a.x); r[1] = f2bf(a.y); r[2] = f2bf(a.z); r[3] = f2bf(a.w);
  r[4] = f2bf(b.x); r[5] = f2bf(b.y); r[6] = f2bf(b.z); r[7] = f2bf(b.w);
  *(u16x8*)(out + i) = r;
}

// ---------------- transpose+cast fp32 [R][Cin] -> bf16 [Cin][R] ----------------
__global__ void transpose_cast_f32_k(const float* __restrict__ in, u16* __restrict__ outp,
                                     int R, int Cin) {
  __shared__ u16 tile[64][72];
  const int c0 = blockIdx.x * 64, r0 = blockIdx.y * 64;
  const int t = threadIdx.x;
  const int r = t >> 2, cs = (t & 3) * 16;
  const float* src = in + (size_t)(r0 + r) * Cin + c0 + cs;
#pragma unroll
  for (int q = 0; q < 4; ++q) {
    float4 v = *(const float4*)(src + q * 4);
    tile[r][cs + q * 4 + 0] = f2bf(v.x);
    tile[r][cs + q * 4 + 1] = f2bf(v.y);
    tile[r][cs + q * 4 + 2] = f2bf(v.z);
    tile[r][cs + q * 4 + 3] = f2bf(v.w);
  }
  __syncthreads();
  u16x8 w0, w1;
#pragma unroll
  for (int q = 0; q < 8; ++q) { w0[q] = tile[cs + q][r]; w1[q] = tile[cs + 8 + q][r]; }
  u16* dst = outp + (size_t)(c0 + r) * R + r0 + cs;
  *(u16x8*)dst = w0;
  *(u16x8*)(dst + 8) = w1;
}

// ---------------- transpose bf16 V [bh][T][D] -> Vt [bh][D][T] ----------------
__global__ void transpose_v_k(const u16* __restrict__ V, u16* __restrict__ Vt) {
  __shared__ u16 tile[64][72];
  const int t0 = blockIdx.x * 64, d0 = blockIdx.y * 64, bh = blockIdx.z;
  const int t = threadIdx.x;
  const int r = t >> 2, cs = (t & 3) * 16;
  const u16* src = V + ((size_t)bh * 2048 + t0 + r) * 128 + d0 + cs;
  u16x8 a0 = *(const u16x8*)src;
  u16x8 a1 = *(const u16x8*)(src + 8);
#pragma unroll
  for (int q = 0; q < 8; ++q) { tile[r][cs + q] = a0[q]; tile[r][cs + 8 + q] = a1[q]; }
  __syncthreads();
  u16x8 w0, w1;
#pragma unroll
  for (int q = 0; q < 8; ++q) { w0[q] = tile[cs + q][r]; w1[q] = tile[cs + 8 + q][r]; }
  u16* dst = Vt + ((size_t)bh * 128 + d0 + r) * 2048 + t0 + cs;
  *(u16x8*)dst = w0;
  *(u16x8*)(dst + 8) = w1;
}

// ---------------- GEMM 256x256, BK=64, 8 waves, 4-phase/K-tile fine interleave ----
// LDS chunk map (1 chunk = 16B = 8 bf16 along K):
//   A: chunk = abuf*2048 + qm*1024 + khi*128 + wrh*64 + rlo
//      holds A[mt*256 + wrh*128 + qm*64 + rlo][k0 + khi*8 .. +7]
//   B: chunk = 4096 + bbuf*2048 + qn*1024 + khi*128 + wcb*32 + rlo
//      holds Bt[nt*256 + wcb*64 + qn*32 + rlo][k0 + khi*8 .. +7]
// Stage unit = 16KB contiguous (1024 chunks), 2 x gld_lds16 per thread, linear dest.
template <int EPI>
__global__ __launch_bounds__(512, 2) void gemm256(
    const u16* __restrict__ A, const u16* __restrict__ Bt,
    const float* __restrict__ bias,
    u16* __restrict__ o0, u16* __restrict__ o1, u16* __restrict__ o2,
    float* __restrict__ ofp, int Ntiles, int Kdim) {
  __shared__ __align__(128) u16 sm[65536];  // 128 KB
  const int nwg = gridDim.x;
  const int orig = blockIdx.x;
  const int qq = nwg >> 3;                        // grids are multiples of 8
  const int bid = (orig & 7) * qq + (orig >> 3);  // bijective XCD swizzle
  const int mt = bid / Ntiles, nt = bid % Ntiles;
  const int tid = threadIdx.x, lane = tid & 63, wave = tid >> 6;
  const int wr = wave >> 2, wc = wave & 3;        // 2M x 4N waves, 128x64 out each
  const int l15 = lane & 15, lhi = lane >> 4;
  f32x4 acc[8][4] = {};
  const int nK = Kdim >> 6;

#define VMA(n) asm volatile("s_waitcnt vmcnt(" #n ")" ::: "memory")
#define BARK   asm volatile("s_barrier" ::: "memory")
#define LG0                                                   \
  do {                                                        \
    asm volatile("s_waitcnt lgkmcnt(0)" ::: "memory");        \
    __builtin_amdgcn_sched_barrier(0);                        \
  } while (0)
#define DSA(qm)                                                                          \
  do {                                                                                   \
    _Pragma("unroll") for (int mi = 0; mi < 4; ++mi)                                     \
    _Pragma("unroll") for (int kk = 0; kk < 2; ++kk)                                     \
      af[mi * 2 + kk] = *(const s16x8*)&sm[(size_t)(cA + (qm) * 1024 +                   \
          (kk * 4 + lhi) * 128 + wr * 64 + mi * 16 + l15) * 8];                          \
  } while (0)
#define DSB(qn)                                                                          \
  do {                                                                                   \
    _Pragma("unroll") for (int ni = 0; ni < 2; ++ni)                                     \
    _Pragma("unroll") for (int kk = 0; kk < 2; ++kk)                                     \
      bf[ni * 2 + kk] = *(const s16x8*)&sm[(size_t)(cB + (qn) * 1024 +                   \
          (kk * 4 + lhi) * 128 + wc * 32 + ni * 16 + l15) * 8];                          \
  } while (0)
#define STA(qm, k0, sbase)                                                               \
  do {                                                                                   \
    _Pragma("unroll") for (int l = 0; l < 2; ++l)                                        \
      gld_lds16(A + (size_t)(mt * 256 + (wave & 1) * 128 + (qm) * 64 + lane) * Kdim +    \
                    (k0) + (l * 4 + (wave >> 1)) * 8,                                    \
                &sm[(size_t)((sbase) + (qm) * 1024 + l * 512 + wave * 64) * 8]);         \
  } while (0)
#define STB(qn, k0, sbase)                                                               \
  do {                                                                                   \
    _Pragma("unroll") for (int l = 0; l < 2; ++l)                                        \
      gld_lds16(Bt + (size_t)(nt * 256 + ((wave & 1) * 2 + (lane >> 5)) * 64 +           \
                              (qn) * 32 + (lane & 31)) * Kdim +                          \
                     (k0) + (l * 4 + (wave >> 1)) * 8,                                   \
                &sm[(size_t)((sbase) + (qn) * 1024 + l * 512 + wave * 64) * 8]);         \
  } while (0)
#define MM(qm, qn)                                                                       \
  do {                                                                                   \
    __builtin_amdgcn_s_setprio(1);                                                       \
    _Pragma("unroll") for (int mi = 0; mi < 4; ++mi)                                     \
    _Pragma("unroll") for (int ni = 0; ni < 2; ++ni)                                     \
    _Pragma("unroll") for (int kk = 0; kk < 2; ++kk)                                     \
      acc[(qm) * 4 + mi][(qn) * 2 + ni] = __builtin_amdgcn_mfma_f32_16x16x32_bf16(       \
          af[mi * 2 + kk], bf[ni * 2 + kk], acc[(qm) * 4 + mi][(qn) * 2 + ni], 0, 0, 0); \
    __builtin_amdgcn_s_setprio(0);                                                       \
  } while (0)

  // prologue: stage tile 0 into buf0, issue order U0=A0,U1=B0,U2=B1,U3=A1
  STA(0, 0, 0); STB(0, 0, 4096); STB(1, 0, 4096); STA(1, 0, 0);
  VMA(4);  // U0,U1 landed (all waves re-confirmed by barrier)
  BARK;

  for (int t = 0; t < nK; ++t) {
    const int cA = (t & 1) * 2048, cB = 4096 + (t & 1) * 2048;
    const int sA = ((t & 1) ^ 1) * 2048, sB = 4096 + ((t & 1) ^ 1) * 2048;
    const int k1 = (t + 1) << 6;
    const bool st = (t + 1 < nK);
    s16x8 af[8], bf[4];
    // ph0: quadrant (0,0); ensures U2(t) for ph1
    DSA(0); DSB(0);
    if (st) { STA(0, k1, sA); VMA(4); } else { VMA(2); }
    BARK; LG0; MM(0, 0); BARK;
    // ph1: quadrant (0,1); ensures U3(t) for ph2
    DSB(1);
    if (st) { STB(0, k1, sB); VMA(4); } else { VMA(0); }
    BARK; LG0; MM(0, 1); BARK;
    // ph2: quadrant (1,1); no wait needed for ph3 (re-reads B0)
    DSA(1);
    if (st) STB(1, k1, sB);
    BARK; LG0; MM(1, 1); BARK;
    // ph3: quadrant (1,0); ensures U0,U1(t+1) for next ph0
    DSB(0);
    if (st) { STA(1, k1, sA); VMA(4); }
    BARK; LG0; MM(1, 0); BARK;
  }
#undef VMA
#undef BARK
#undef LG0
#undef DSA
#undef DSB
#undef STA
#undef STB
#undef MM

  const int row0 = mt * 256 + wr * 128;
  const int col0 = nt * 256 + wc * 64;
  float bcol[4];
#pragma unroll
  for (int ni = 0; ni < 4; ++ni) bcol[ni] = bias[col0 + ni * 16 + l15];
  if constexpr (EPI == 0) {
#pragma unroll
    for (int ni = 0; ni < 4; ++ni) {
      int cc = col0 + ni * 16 + l15;
      int which = cc >> 11, h = (cc >> 7) & 15, d = cc & 127;
      u16* o = (which == 0) ? o0 : (which == 1) ? o1 : o2;
#pragma unroll
      for (int mi = 0; mi < 8; ++mi)
#pragma unroll
        for (int j = 0; j < 4; ++j) {
          int row = row0 + mi * 16 + lhi * 4 + j;
          int bb = row >> 11, tt = row & 2047;
          o[(((size_t)bb * 16 + h) * 2048 + tt) * 128 + d] = f2bf(acc[mi][ni][j] + bcol[ni]);
        }
    }
  } else {
#pragma unroll
    for (int mi = 0; mi < 8; ++mi)
#pragma unroll
      for (int j = 0; j < 4; ++j) {
        int row = row0 + mi * 16 + lhi * 4 + j;
#pragma unroll
        for (int ni = 0; ni < 4; ++ni)
          ofp[(size_t)row * 2048 + col0 + ni * 16 + l15] = acc[mi][ni][j] + bcol[ni];
      }
  }
}

// ---------------- flash attention: 64 q-rows/block, 4 waves x 16 rows ----------------
__global__ __launch_bounds__(256, 2) void attn_k(
    const u16* __restrict__ Q, const u16* __restrict__ Kg,
    const u16* __restrict__ Vt, u16* __restrict__ Y) {
  __shared__ u16 Ks[8192];        // 16 dhi x 64 key, 16B chunks
  __shared__ u16 Vs[8192];        // 8 khi x 128 d, 16B chunks
  __shared__ u16 Ps[4][16 * 72];  // per-wave P tile, padded rows
  const int qt = blockIdx.x, bh = blockIdx.y;
  const int tid = threadIdx.x, lane = tid & 63, wave = tid >> 6;
  const int r0 = qt * 64 + wave * 16;
  const size_t bhT = (size_t)bh * 2048;

  s16x8 qf[4];
#pragma unroll
  for (int kk = 0; kk < 4; ++kk)
    qf[kk] = *(const s16x8*)&Q[(bhT + r0 + (lane & 15)) * 128 + kk * 32 + (lane >> 4) * 8];

  f32x4 o[8] = {};
  float m_[4], l_[4];
#pragma unroll
  for (int j = 0; j < 4; ++j) { m_[j] = -1e30f; l_[j] = 0.f; }
  const float sc = 0.08838834764831845f * 1.4426950408889634f;  // 1/sqrt(128) * log2(e)

  for (int it = 0; it <= qt; ++it) {
    const int j0 = it * 64;
    __syncthreads();  // previous tile's LDS reads done before restage
#pragma unroll
    for (int j = 0; j < 4; ++j) {
      int idx = (wave * 4 + j) * 64 + lane;
      int dhi = idx >> 6, key = idx & 63;
      gld_lds16(Kg + (bhT + j0 + key) * 128 + dhi * 8, &Ks[(wave * 4 + j) * 512]);
      int khi = idx >> 7, d = idx & 127;
      gld_lds16(Vt + ((size_t)bh * 128 + d) * 2048 + j0 + khi * 8, &Vs[(wave * 4 + j) * 512]);
    }
    __syncthreads();  // drains vmcnt: K/V staged

    // S = Q K^T (per wave: 16 q-rows x 64 keys)
    f32x4 s[4] = {};
#pragma unroll
    for (int nc = 0; nc < 4; ++nc) {
#pragma unroll
      for (int kk = 0; kk < 4; ++kk) {
        s16x8 kf = *(const s16x8*)&Ks[((kk * 4 + (lane >> 4)) * 64 + nc * 16 + (lane & 15)) * 8];
        s[nc] = __builtin_amdgcn_mfma_f32_16x16x32_bf16(qf[kk], kf, s[nc], 0, 0, 0);
      }
    }
    const bool lastT = (it == qt);
    float rmax[4];
#pragma unroll
    for (int j = 0; j < 4; ++j) rmax[j] = -1e30f;
#pragma unroll
    for (int nc = 0; nc < 4; ++nc)
#pragma unroll
      for (int j = 0; j < 4; ++j) {
        float v = s[nc][j] * sc;
        if (lastT && (j0 + nc * 16 + (lane & 15)) > (r0 + (lane >> 4) * 4 + j)) v = -1e30f;
        s[nc][j] = v;
        rmax[j] = fmaxf(rmax[j], v);
      }
#pragma unroll
    for (int off = 1; off < 16; off <<= 1)
#pragma unroll
      for (int j = 0; j < 4; ++j) rmax[j] = fmaxf(rmax[j], __shfl_xor(rmax[j], off));

    float al[4], rsum[4];
#pragma unroll
    for (int j = 0; j < 4; ++j) {
      float mn = fmaxf(m_[j], rmax[j]);
      al[j] = exp2f(m_[j] - mn);
      m_[j] = mn;
      rsum[j] = 0.f;
    }
#pragma unroll
    for (int nc = 0; nc < 4; ++nc)
#pragma unroll
      for (int j = 0; j < 4; ++j) {
        float p = exp2f(s[nc][j] - m_[j]);
        rsum[j] += p;
        Ps[wave][((lane >> 4) * 4 + j) * 72 + nc * 16 + (lane & 15)] = f2bf(p);
      }
#pragma unroll
    for (int off = 1; off < 16; off <<= 1)
#pragma unroll
      for (int j = 0; j < 4; ++j) rsum[j] += __shfl_xor(rsum[j], off);
#pragma unroll
    for (int j = 0; j < 4; ++j) l_[j] = l_[j] * al[j] + rsum[j];
#pragma unroll
    for (int di = 0; di < 8; ++di)
#pragma unroll
      for (int j = 0; j < 4; ++j) o[di][j] *= al[j];

    // O += P V  (P via LDS round-trip to get A-fragment layout)
#pragma unroll
    for (int kk2 = 0; kk2 < 2; ++kk2) {
      s16x8 pf = *(const s16x8*)&Ps[wave][(lane & 15) * 72 + kk2 * 32 + (lane >> 4) * 8];
#pragma unroll
      for (int di = 0; di < 8; ++di) {
        s16x8 vf = *(const s16x8*)&Vs[((kk2 * 4 + (lane >> 4)) * 128 + di * 16 + (lane & 15)) * 8];
        o[di] = __builtin_amdgcn_mfma_f32_16x16x32_bf16(pf, vf, o[di], 0, 0, 0);
      }
    }
  }

  float rl[4];
#pragma unroll
  for (int j = 0; j < 4; ++j) rl[j] = 1.0f / l_[j];
  const int b = bh >> 4, h = bh & 15;
#pragma unroll
  for (int di = 0; di < 8; ++di)
#pragma unroll
    for (int j = 0; j < 4; ++j) {
      int row = b * 2048 + r0 + (lane >> 4) * 4 + j;
      int col = h * 128 + di * 16 + (lane & 15);
      Y[(size_t)row * 2048 + col] = f2bf(o[di][j] * rl[j]);
    }
}

extern "C" void kernel_launch(void* const* d_in, const int* in_sizes, int n_in,
                              void* d_out, int out_size, void* d_ws, size_t ws_size,
                              hipStream_t stream) {
  const float* x      = (const float*)d_in[0];
  const float* w_attn = (const float*)d_in[1];
  const float* b_attn = (const float*)d_in[2];
  const float* w_proj = (const float*)d_in[3];
  const float* b_proj = (const float*)d_in[4];
  float* out = (float*)d_out;

  char* ws = (char*)d_ws;
  u16* xb  = (u16*)(ws);                      // x bf16 [8192][2048]
  u16* waT = (u16*)(ws + 33554432ull);        // w_attn^T bf16 [6144][2048]
  u16* wpT = (u16*)(ws + 58720256ull);        // w_proj^T bf16 [2048][2048]
  u16* Qb  = (u16*)(ws + 67108864ull);        // [B,H,T,D]
  u16* Kb  = (u16*)(ws + 100663296ull);
  u16* Vb  = (u16*)(ws + 134217728ull);
  u16* Vtb = (u16*)(ws + 167772160ull);       // [B,H,D,T]
  u16* Yb  = xb;                              // reuse (xb dead after gemm1)

  cast_f32_bf16_k<<<8192, 256, 0, stream>>>(x, xb);
  transpose_cast_f32_k<<<dim3(96, 32), 256, 0, stream>>>(w_attn, waT, 2048, 6144);
  transpose_cast_f32_k<<<dim3(32, 32), 256, 0, stream>>>(w_proj, wpT, 2048, 2048);
  gemm256<0><<<32 * 24, 512, 0, stream>>>(xb, waT, b_attn, Qb, Kb, Vb, nullptr, 24, 2048);
  transpose_v_k<<<dim3(32, 2, 64), 256, 0, stream>>>(Vb, Vtb);
  attn_k<<<dim3(32, 64), 256, 0, stream>>>(Qb, Kb, Vtb, Yb);
  gemm256<1><<<32 * 8, 512, 0, stream>>>(Yb, wpT, b_proj, nullptr, nullptr, nullptr, out, 8, 2048);
}

// Round 4
// 584.163 us; speedup vs baseline: 1.6504x; 1.2589x over previous
//
#include <hip/hip_runtime.h>
#include <cstdint>

typedef unsigned short u16;
typedef u16   u16x8 __attribute__((ext_vector_type(8)));
typedef short s16x8 __attribute__((ext_vector_type(8)));
typedef float f32x4 __attribute__((ext_vector_type(4)));

__device__ __forceinline__ u16 f2bf(float f) {
  union { float f; unsigned u; } v; v.f = f;
  unsigned u = v.u;
  return (u16)((u + 0x7fffu + ((u >> 16) & 1u)) >> 16);
}

__device__ __forceinline__ void gld_lds16(const u16* g, u16* l) {
  __builtin_amdgcn_global_load_lds((const __attribute__((address_space(1))) void*)g,
                                   (__attribute__((address_space(3))) void*)l, 16, 0, 0);
}

// ---------------- elementwise cast fp32 -> bf16 ----------------
__global__ void cast_f32_bf16_k(const float* __restrict__ in, u16* __restrict__ out) {
  size_t i = ((size_t)blockIdx.x * 256 + threadIdx.x) * 8;
  float4 a = *(const float4*)(in + i);
  float4 b = *(const float4*)(in + i + 4);
  u16x8 r;
  r[0] = f2bf(a.x); r[1] = f2bf(a.y); r[2] = f2bf(a.z); r[3] = f2bf(a.w);
  r[4] = f2bf(b.x); r[5] = f2bf(b.y); r[6] = f2bf(b.z); r[7] = f2bf(b.w);
  *(u16x8*)(out + i) = r;
}

// ---------------- transpose+cast fp32 [R][Cin] -> bf16 [Cin][R] ----------------
__global__ void transpose_cast_f32_k(const float* __restrict__ in, u16* __restrict__ outp,
                                     int R, int Cin) {
  __shared__ u16 tile[64][72];
  const int c0 = blockIdx.x * 64, r0 = blockIdx.y * 64;
  const int t = threadIdx.x;
  const int r = t >> 2, cs = (t & 3) * 16;
  const float* src = in + (size_t)(r0 + r) * Cin + c0 + cs;
#pragma unroll
  for (int q = 0; q < 4; ++q) {
    float4 v = *(const float4*)(src + q * 4);
    tile[r][cs + q * 4 + 0] = f2bf(v.x);
    tile[r][cs + q * 4 + 1] = f2bf(v.y);
    tile[r][cs + q * 4 + 2] = f2bf(v.z);
    tile[r][cs + q * 4 + 3] = f2bf(v.w);
  }
  __syncthreads();
  u16x8 w0, w1;
#pragma unroll
  for (int q = 0; q < 8; ++q) { w0[q] = tile[cs + q][r]; w1[q] = tile[cs + 8 + q][r]; }
  u16* dst = outp + (size_t)(c0 + r) * R + r0 + cs;
  *(u16x8*)dst = w0;
  *(u16x8*)(dst + 8) = w1;
}

// ---------------- transpose bf16 V [bh][T][D] -> Vt [bh][D][T] ----------------
__global__ void transpose_v_k(const u16* __restrict__ V, u16* __restrict__ Vt) {
  __shared__ u16 tile[64][72];
  const int t0 = blockIdx.x * 64, d0 = blockIdx.y * 64, bh = blockIdx.z;
  const int t = threadIdx.x;
  const int r = t >> 2, cs = (t & 3) * 16;
  const u16* src = V + ((size_t)bh * 2048 + t0 + r) * 128 + d0 + cs;
  u16x8 a0 = *(const u16x8*)src;
  u16x8 a1 = *(const u16x8*)(src + 8);
#pragma unroll
  for (int q = 0; q < 8; ++q) { tile[r][cs + q] = a0[q]; tile[r][cs + 8 + q] = a1[q]; }
  __syncthreads();
  u16x8 w0, w1;
#pragma unroll
  for (int q = 0; q < 8; ++q) { w0[q] = tile[cs + q][r]; w1[q] = tile[cs + 8 + q][r]; }
  u16* dst = Vt + ((size_t)bh * 128 + d0 + r) * 2048 + t0 + cs;
  *(u16x8*)dst = w0;
  *(u16x8*)(dst + 8) = w1;
}

// ---------------- GEMM 256x256, BK=64, 8 waves, 4-phase/K-tile fine interleave ----
template <int EPI>
__global__ __launch_bounds__(512, 2) void gemm256(
    const u16* __restrict__ A, const u16* __restrict__ Bt,
    const float* __restrict__ bias,
    u16* __restrict__ o0, u16* __restrict__ o1, u16* __restrict__ o2,
    float* __restrict__ ofp, int Ntiles, int Kdim) {
  __shared__ __align__(128) u16 sm[65536];  // 128 KB
  const int nwg = gridDim.x;
  const int orig = blockIdx.x;
  const int qq = nwg >> 3;                        // grids are multiples of 8
  const int bid = (orig & 7) * qq + (orig >> 3);  // bijective XCD swizzle
  const int mt = bid / Ntiles, nt = bid % Ntiles;
  const int tid = threadIdx.x, lane = tid & 63, wave = tid >> 6;
  const int wr = wave >> 2, wc = wave & 3;        // 2M x 4N waves, 128x64 out each
  const int l15 = lane & 15, lhi = lane >> 4;
  f32x4 acc[8][4] = {};
  const int nK = Kdim >> 6;

#define VMA(n) asm volatile("s_waitcnt vmcnt(" #n ")" ::: "memory")
#define BARK   asm volatile("s_barrier" ::: "memory")
#define LG0                                                   \
  do {                                                        \
    asm volatile("s_waitcnt lgkmcnt(0)" ::: "memory");        \
    __builtin_amdgcn_sched_barrier(0);                        \
  } while (0)
#define DSA(qm)                                                                          \
  do {                                                                                   \
    _Pragma("unroll") for (int mi = 0; mi < 4; ++mi)                                     \
    _Pragma("unroll") for (int kk = 0; kk < 2; ++kk)                                     \
      af[mi * 2 + kk] = *(const s16x8*)&sm[(size_t)(cA + (qm) * 1024 +                   \
          (kk * 4 + lhi) * 128 + wr * 64 + mi * 16 + l15) * 8];                          \
  } while (0)
#define DSB(qn)                                                                          \
  do {                                                                                   \
    _Pragma("unroll") for (int ni = 0; ni < 2; ++ni)                                     \
    _Pragma("unroll") for (int kk = 0; kk < 2; ++kk)                                     \
      bf[ni * 2 + kk] = *(const s16x8*)&sm[(size_t)(cB + (qn) * 1024 +                   \
          (kk * 4 + lhi) * 128 + wc * 32 + ni * 16 + l15) * 8];                          \
  } while (0)
#define STA(qm, k0, sbase)                                                               \
  do {                                                                                   \
    _Pragma("unroll") for (int l = 0; l < 2; ++l)                                        \
      gld_lds16(A + (size_t)(mt * 256 + (wave & 1) * 128 + (qm) * 64 + lane) * Kdim +    \
                    (k0) + (l * 4 + (wave >> 1)) * 8,                                    \
                &sm[(size_t)((sbase) + (qm) * 1024 + l * 512 + wave * 64) * 8]);         \
  } while (0)
#define STB(qn, k0, sbase)                                                               \
  do {                                                                                   \
    _Pragma("unroll") for (int l = 0; l < 2; ++l)                                        \
      gld_lds16(Bt + (size_t)(nt * 256 + ((wave & 1) * 2 + (lane >> 5)) * 64 +           \
                              (qn) * 32 + (lane & 31)) * Kdim +                          \
                     (k0) + (l * 4 + (wave >> 1)) * 8,                                   \
                &sm[(size_t)((sbase) + (qn) * 1024 + l * 512 + wave * 64) * 8]);         \
  } while (0)
#define MM(qm, qn)                                                                       \
  do {                                                                                   \
    __builtin_amdgcn_s_setprio(1);                                                       \
    _Pragma("unroll") for (int mi = 0; mi < 4; ++mi)                                     \
    _Pragma("unroll") for (int ni = 0; ni < 2; ++ni)                                     \
    _Pragma("unroll") for (int kk = 0; kk < 2; ++kk)                                     \
      acc[(qm) * 4 + mi][(qn) * 2 + ni] = __builtin_amdgcn_mfma_f32_16x16x32_bf16(       \
          af[mi * 2 + kk], bf[ni * 2 + kk], acc[(qm) * 4 + mi][(qn) * 2 + ni], 0, 0, 0); \
    __builtin_amdgcn_s_setprio(0);                                                       \
  } while (0)

  STA(0, 0, 0); STB(0, 0, 4096); STB(1, 0, 4096); STA(1, 0, 0);
  VMA(4);
  BARK;

  for (int t = 0; t < nK; ++t) {
    const int cA = (t & 1) * 2048, cB = 4096 + (t & 1) * 2048;
    const int sA = ((t & 1) ^ 1) * 2048, sB = 4096 + ((t & 1) ^ 1) * 2048;
    const int k1 = (t + 1) << 6;
    const bool st = (t + 1 < nK);
    s16x8 af[8], bf[4];
    DSA(0); DSB(0);
    if (st) { STA(0, k1, sA); VMA(4); } else { VMA(2); }
    BARK; LG0; MM(0, 0); BARK;
    DSB(1);
    if (st) { STB(0, k1, sB); VMA(4); } else { VMA(0); }
    BARK; LG0; MM(0, 1); BARK;
    DSA(1);
    if (st) STB(1, k1, sB);
    BARK; LG0; MM(1, 1); BARK;
    DSB(0);
    if (st) { STA(1, k1, sA); VMA(4); }
    BARK; LG0; MM(1, 0); BARK;
  }
#undef VMA
#undef BARK
#undef LG0
#undef DSA
#undef DSB
#undef STA
#undef STB
#undef MM

  const int row0 = mt * 256 + wr * 128;
  const int col0 = nt * 256 + wc * 64;
  float bcol[4];
#pragma unroll
  for (int ni = 0; ni < 4; ++ni) bcol[ni] = bias[col0 + ni * 16 + l15];
  if constexpr (EPI == 0) {
#pragma unroll
    for (int ni = 0; ni < 4; ++ni) {
      int cc = col0 + ni * 16 + l15;
      int which = cc >> 11, h = (cc >> 7) & 15, d = cc & 127;
      u16* o = (which == 0) ? o0 : (which == 1) ? o1 : o2;
#pragma unroll
      for (int mi = 0; mi < 8; ++mi)
#pragma unroll
        for (int j = 0; j < 4; ++j) {
          int row = row0 + mi * 16 + lhi * 4 + j;
          int bb = row >> 11, tt = row & 2047;
          o[(((size_t)bb * 16 + h) * 2048 + tt) * 128 + d] = f2bf(acc[mi][ni][j] + bcol[ni]);
        }
    }
  } else {
#pragma unroll
    for (int mi = 0; mi < 8; ++mi)
#pragma unroll
      for (int j = 0; j < 4; ++j) {
        int row = row0 + mi * 16 + lhi * 4 + j;
#pragma unroll
        for (int ni = 0; ni < 4; ++ni)
          ofp[(size_t)row * 2048 + col0 + ni * 16 + l15] = acc[mi][ni][j] + bcol[ni];
      }
  }
}

// ---------------- flash attention v2: 128 q-rows/block, 8 waves, mirror-paired ----
// Block p handles q-tiles {p, 15-p} sequentially -> exactly 34 KV-iters/block.
// K/V for next tile prefetched to registers (T14), written to LDS after WAR barrier.
__global__ __launch_bounds__(512, 4) void attn_k(
    const u16* __restrict__ Q, const u16* __restrict__ Kg,
    const u16* __restrict__ Vt, u16* __restrict__ Y) {
  __shared__ u16 Ks[8192];        // 16KB: chunk ci = dhi*64+key -> K[key][dhi*8..+7]
  __shared__ u16 Vs[8192];        // 16KB: chunk ci = khi*128+d  -> Vt[d][khi*8..+7]
  __shared__ u16 Ps[8][16 * 72];  // per-wave P tile, padded rows
  const int p = blockIdx.x, bh = blockIdx.y;
  const int tid = threadIdx.x, lane = tid & 63, wave = tid >> 6;
  const int l15 = lane & 15, lhi = lane >> 4;
  const size_t bhT = (size_t)bh * 2048;
  const int b = bh >> 4, h = bh & 15;
  const float sc = 0.08838834764831845f * 1.4426950408889634f;  // 1/sqrt(128)*log2(e)

  for (int hf = 0; hf < 2; ++hf) {
    const int qt = hf ? 15 - p : p;          // 128-row q-tile index, 0..15
    const int r0 = qt * 128 + wave * 16;
    const int last = 2 * qt + 1;             // KV tiles 0..last (64 keys each)

    s16x8 qf[4];
#pragma unroll
    for (int kk = 0; kk < 4; ++kk)
      qf[kk] = *(const s16x8*)&Q[(bhT + r0 + l15) * 128 + kk * 32 + lhi * 8];

    f32x4 o[8] = {};
    float m_[4], l_[4];
#pragma unroll
    for (int j = 0; j < 4; ++j) { m_[j] = -1e30f; l_[j] = 0.f; }

    // prologue: stage KV tile 0 (WAR barrier vs previous half's reads)
    __syncthreads();
#pragma unroll
    for (int c = 0; c < 2; ++c) {
      int ci = c * 512 + tid;
      int dhi = ci >> 6, key = ci & 63;
      gld_lds16(Kg + (bhT + key) * 128 + dhi * 8, &Ks[(c * 512 + wave * 64) * 8]);
      int khi = ci >> 7, d = ci & 127;
      gld_lds16(Vt + ((size_t)bh * 128 + d) * 2048 + khi * 8, &Vs[(c * 512 + wave * 64) * 8]);
    }
    __syncthreads();

    for (int it = 0; it <= last; ++it) {
      const int j0 = it * 64;
      const bool have_next = (it < last);
      u16x8 kpre[2], vpre[2];
      if (have_next) {
        const int j1 = j0 + 64;
#pragma unroll
        for (int c = 0; c < 2; ++c) {
          int ci = c * 512 + tid;
          int dhi = ci >> 6, key = ci & 63;
          kpre[c] = *(const u16x8*)&Kg[(bhT + j1 + key) * 128 + dhi * 8];
          int khi = ci >> 7, d = ci & 127;
          vpre[c] = *(const u16x8*)&Vt[((size_t)bh * 128 + d) * 2048 + j1 + khi * 8];
        }
      }

      if (j0 <= r0 + 15) {  // wave has at least one unmasked (row,key) pair
        // S = Q K^T (16 q-rows x 64 keys)
        f32x4 s[4] = {};
#pragma unroll
        for (int nc = 0; nc < 4; ++nc)
#pragma unroll
          for (int kk = 0; kk < 4; ++kk) {
            s16x8 kf = *(const s16x8*)&Ks[((kk * 4 + lhi) * 64 + nc * 16 + l15) * 8];
            s[nc] = __builtin_amdgcn_mfma_f32_16x16x32_bf16(qf[kk], kf, s[nc], 0, 0, 0);
          }
        const bool maskt = (j0 + 63 > r0);
        float rmax[4];
#pragma unroll
        for (int j = 0; j < 4; ++j) rmax[j] = -1e30f;
#pragma unroll
        for (int nc = 0; nc < 4; ++nc)
#pragma unroll
          for (int j = 0; j < 4; ++j) {
            float v = s[nc][j] * sc;
            if (maskt && (j0 + nc * 16 + l15) > (r0 + lhi * 4 + j)) v = -1e30f;
            s[nc][j] = v;
            rmax[j] = fmaxf(rmax[j], v);
          }
#pragma unroll
        for (int off = 1; off < 16; off <<= 1)
#pragma unroll
          for (int j = 0; j < 4; ++j) rmax[j] = fmaxf(rmax[j], __shfl_xor(rmax[j], off));

        float al[4], rsum[4];
#pragma unroll
        for (int j = 0; j < 4; ++j) {
          float mn = fmaxf(m_[j], rmax[j]);
          al[j] = exp2f(m_[j] - mn);
          m_[j] = mn;
          rsum[j] = 0.f;
        }
#pragma unroll
        for (int nc = 0; nc < 4; ++nc)
#pragma unroll
          for (int j = 0; j < 4; ++j) {
            float pv = exp2f(s[nc][j] - m_[j]);
            rsum[j] += pv;
            Ps[wave][(lhi * 4 + j) * 72 + nc * 16 + l15] = f2bf(pv);
          }
#pragma unroll
        for (int off = 1; off < 16; off <<= 1)
#pragma unroll
          for (int j = 0; j < 4; ++j) rsum[j] += __shfl_xor(rsum[j], off);
#pragma unroll
        for (int j = 0; j < 4; ++j) l_[j] = l_[j] * al[j] + rsum[j];
#pragma unroll
        for (int di = 0; di < 8; ++di)
#pragma unroll
          for (int j = 0; j < 4; ++j) o[di][j] *= al[j];

        // O += P V
#pragma unroll
        for (int kk2 = 0; kk2 < 2; ++kk2) {
          s16x8 pf = *(const s16x8*)&Ps[wave][l15 * 72 + kk2 * 32 + lhi * 8];
#pragma unroll
          for (int di = 0; di < 8; ++di) {
            s16x8 vf = *(const s16x8*)&Vs[((kk2 * 4 + lhi) * 128 + di * 16 + l15) * 8];
            o[di] = __builtin_amdgcn_mfma_f32_16x16x32_bf16(pf, vf, o[di], 0, 0, 0);
          }
        }
      }

      if (have_next) {
        __syncthreads();  // all waves done reading Ks/Vs
#pragma unroll
        for (int c = 0; c < 2; ++c) {
          *(u16x8*)&Ks[(c * 512 + tid) * 8] = kpre[c];
          *(u16x8*)&Vs[(c * 512 + tid) * 8] = vpre[c];
        }
        __syncthreads();  // staged for next iter
      }
    }

    float rl[4];
#pragma unroll
    for (int j = 0; j < 4; ++j) rl[j] = 1.0f / l_[j];
#pragma unroll
    for (int di = 0; di < 8; ++di)
#pragma unroll
      for (int j = 0; j < 4; ++j) {
        int row = b * 2048 + r0 + lhi * 4 + j;
        int col = h * 128 + di * 16 + l15;
        Y[(size_t)row * 2048 + col] = f2bf(o[di][j] * rl[j]);
      }
  }
}

extern "C" void kernel_launch(void* const* d_in, const int* in_sizes, int n_in,
                              void* d_out, int out_size, void* d_ws, size_t ws_size,
                              hipStream_t stream) {
  const float* x      = (const float*)d_in[0];
  const float* w_attn = (const float*)d_in[1];
  const float* b_attn = (const float*)d_in[2];
  const float* w_proj = (const float*)d_in[3];
  const float* b_proj = (const float*)d_in[4];
  float* out = (float*)d_out;

  char* ws = (char*)d_ws;
  u16* xb  = (u16*)(ws);                      // x bf16 [8192][2048]
  u16* waT = (u16*)(ws + 33554432ull);        // w_attn^T bf16 [6144][2048]
  u16* wpT = (u16*)(ws + 58720256ull);        // w_proj^T bf16 [2048][2048]
  u16* Qb  = (u16*)(ws + 67108864ull);        // [B,H,T,D]
  u16* Kb  = (u16*)(ws + 100663296ull);
  u16* Vb  = (u16*)(ws + 134217728ull);
  u16* Vtb = (u16*)(ws + 167772160ull);       // [B,H,D,T]
  u16* Yb  = xb;                              // reuse (xb dead after gemm1)

  cast_f32_bf16_k<<<8192, 256, 0, stream>>>(x, xb);
  transpose_cast_f32_k<<<dim3(96, 32), 256, 0, stream>>>(w_attn, waT, 2048, 6144);
  transpose_cast_f32_k<<<dim3(32, 32), 256, 0, stream>>>(w_proj, wpT, 2048, 2048);
  gemm256<0><<<32 * 24, 512, 0, stream>>>(xb, waT, b_attn, Qb, Kb, Vb, nullptr, 24, 2048);
  transpose_v_k<<<dim3(32, 2, 64), 256, 0, stream>>>(Vb, Vtb);
  attn_k<<<dim3(8, 64), 512, 0, stream>>>(Qb, Kb, Vtb, Yb);
  gemm256<1><<<32 * 8, 512, 0, stream>>>(Yb, wpT, b_proj, nullptr, nullptr, nullptr, out, 8, 2048);
}